// Round 1
// baseline (243.681 us; speedup 1.0000x reference)
//
#include <hip/hip_runtime.h>
#include <stdint.h>

#define DEV __device__ __forceinline__

typedef __attribute__((ext_vector_type(4))) float f32x4;
typedef __attribute__((ext_vector_type(8))) __bf16 bf16x8;
typedef __attribute__((ext_vector_type(8))) unsigned short ushort8;

DEV unsigned short f2bf(float f) {
    union { float f; unsigned int u; } v; v.f = f;
    unsigned int r = v.u + 0x7FFFu + ((v.u >> 16) & 1u);
    return (unsigned short)(r >> 16);
}
DEV float bf2f(unsigned short u) {
    union { unsigned int u; float f; } v; v.u = ((unsigned int)u) << 16;
    return v.f;
}
// XOR-swizzle a linear LDS byte offset (128B rows): byte ^= ((row&7)<<4)
DEV int swz(int o) { return o ^ ((o >> 3) & 0x70); }

DEV void gload_lds16(const void* gptr, void* lptr) {
    __builtin_amdgcn_global_load_lds(
        (const __attribute__((address_space(1))) unsigned int*)gptr,
        (__attribute__((address_space(3))) unsigned int*)lptr, 16, 0, 0);
}

// ---------------- fp32 -> bf16 convert of q,k,v ----------------
__global__ void k_convert(const float* __restrict__ q, const float* __restrict__ k,
                          const float* __restrict__ v, unsigned short* __restrict__ qb,
                          unsigned short* __restrict__ kb, unsigned short* __restrict__ vb) {
    const int z = blockIdx.z;
    const float* src = z == 0 ? q : (z == 1 ? k : v);
    unsigned short* dst = z == 0 ? qb : (z == 1 ? kb : vb);
    const size_t idx = ((size_t)blockIdx.x * 256 + threadIdx.x) * 8;
    f32x4 a = *(const f32x4*)(src + idx);
    f32x4 b = *(const f32x4*)(src + idx + 4);
    ushort8 o;
    o[0] = f2bf(a[0]); o[1] = f2bf(a[1]); o[2] = f2bf(a[2]); o[3] = f2bf(a[3]);
    o[4] = f2bf(b[0]); o[5] = f2bf(b[1]); o[6] = f2bf(b[2]); o[7] = f2bf(b[3]);
    *(ushort8*)(dst + idx) = o;
}

// ---------------- W (fp32 [k][n]) -> Wt (bf16 [n][k]) ----------------
__global__ void k_convw(const float* __restrict__ Wq, const float* __restrict__ Wk,
                        const float* __restrict__ Wv, unsigned short* __restrict__ wt) {
    __shared__ float tile[64 * 65];
    const int z = blockIdx.z;
    const float* W = z == 0 ? Wq : (z == 1 ? Wk : Wv);
    unsigned short* dst = wt + (size_t)z * 1048576;
    const int k0 = blockIdx.x * 64, n0 = blockIdx.y * 64;
    const int t = threadIdx.x;
#pragma unroll
    for (int i = 0; i < 4; i++) {
        const int idx = i * 256 + t;
        const int row = idx >> 4, c4 = (idx & 15) * 4;
        f32x4 val = *(const f32x4*)(W + (size_t)(k0 + row) * 1024 + n0 + c4);
#pragma unroll
        for (int j = 0; j < 4; j++) tile[row * 65 + c4 + j] = val[j];
    }
    __syncthreads();
#pragma unroll
    for (int i = 0; i < 2; i++) {
        const int idx = i * 256 + t;
        const int nrow = idx >> 3, c8 = (idx & 7) * 8;
        ushort8 o;
#pragma unroll
        for (int j = 0; j < 8; j++) o[j] = f2bf(tile[(c8 + j) * 65 + nrow]);
        *(ushort8*)(dst + (size_t)(n0 + nrow) * 1024 + k0 + c8) = o;
    }
}

// ---------------- projection GEMM: C = A(4096x1024) * Wt^T + bias ----------------
// 128x128 tile, BK=64, 4 waves (2x2 of 64x64), 16x16x32 bf16 MFMA.
// LDS swizzled via pre-swizzled global source (linear global_load_lds dest).
__global__ __launch_bounds__(256) void k_proj(
    const unsigned short* __restrict__ qb, const unsigned short* __restrict__ kb,
    const unsigned short* __restrict__ vb, const unsigned short* __restrict__ wt,
    const float* __restrict__ bq, const float* __restrict__ bk, const float* __restrict__ bv,
    unsigned short* __restrict__ qh, unsigned short* __restrict__ kh,
    unsigned short* __restrict__ vh) {
    const int z = blockIdx.z;
    const unsigned short* A  = z == 0 ? qb : (z == 1 ? kb : vb);
    const unsigned short* Bt = wt + (size_t)z * 1048576;
    const float* bias = z == 0 ? bq : (z == 1 ? bk : bv);
    unsigned short* outp = z == 0 ? qh : (z == 1 ? kh : vh);
    const float scale = z == 0 ? 0.125f : 1.0f;   // fold 1/sqrt(dh) into q

    __shared__ unsigned short sA[128 * 64];
    __shared__ unsigned short sB[128 * 64];

    const int tid = threadIdx.x;
    const int w = tid >> 6, lane = tid & 63;
    const int c = lane & 15, gq = lane >> 4;
    const int wrow = w >> 1, wcol = w & 1;
    const int m0 = blockIdx.y * 128, n0 = blockIdx.x * 128;
    const int lr = lane >> 3;                       // row within 8-row chunk
    const int lcs = ((lane & 7) ^ (lane >> 3)) * 8; // pre-swizzled source col (elems)

    f32x4 acc[4][4] = {};

    for (int kt = 0; kt < 16; kt++) {
        __syncthreads();
        const int kb0 = kt * 64;
#pragma unroll
        for (int i = 0; i < 4; i++) {
            const int rbase = w * 32 + i * 8;
            gload_lds16(A  + (size_t)(m0 + rbase + lr) * 1024 + kb0 + lcs,
                        (char*)sA + rbase * 128);
            gload_lds16(Bt + (size_t)(n0 + rbase + lr) * 1024 + kb0 + lcs,
                        (char*)sB + rbase * 128);
        }
        __syncthreads();
#pragma unroll
        for (int kk = 0; kk < 2; kk++) {
            bf16x8 af[4], bfr[4];
#pragma unroll
            for (int i = 0; i < 4; i++) {
                af[i]  = *(const bf16x8*)((char*)sA +
                          swz((wrow * 64 + i * 16 + c) * 128 + kk * 64 + gq * 16));
                bfr[i] = *(const bf16x8*)((char*)sB +
                          swz((wcol * 64 + i * 16 + c) * 128 + kk * 64 + gq * 16));
            }
#pragma unroll
            for (int mi = 0; mi < 4; mi++)
#pragma unroll
                for (int ni = 0; ni < 4; ni++)
                    acc[mi][ni] = __builtin_amdgcn_mfma_f32_16x16x32_bf16(
                        af[mi], bfr[ni], acc[mi][ni], 0, 0, 0);
        }
    }

    float bvals[4];
#pragma unroll
    for (int ni = 0; ni < 4; ni++) bvals[ni] = bias[n0 + wcol * 64 + ni * 16 + c];

#pragma unroll
    for (int mi = 0; mi < 4; mi++)
#pragma unroll
        for (int ni = 0; ni < 4; ni++) {
            const int n = n0 + wcol * 64 + ni * 16 + c;
            const int head = n >> 6, d = n & 63;
#pragma unroll
            for (int r = 0; r < 4; r++) {
                const int m = m0 + wrow * 64 + mi * 16 + gq * 4 + r;
                const int bb = m >> 10, s = m & 1023;
                const float val = (acc[mi][ni][r] + bvals[ni]) * scale;
                outp[(size_t)((head << 2) + bb) * 65536 + (size_t)s * 64 + d] = f2bf(val);
            }
        }
}

// ---------------- vh [hb][s][d] -> vt [hb][d][s] ----------------
__global__ void k_trv(const unsigned short* __restrict__ vh, unsigned short* __restrict__ vt) {
    __shared__ unsigned int tile[64 * 65];
    const int hb = blockIdx.y, s0 = blockIdx.x * 64;
    const int t = threadIdx.x;
#pragma unroll
    for (int it = 0; it < 2; it++) {
        const int idx = it * 256 + t;
        const int row = idx >> 3, c8 = (idx & 7) * 8;
        ushort8 val = *(const ushort8*)(vh + (size_t)hb * 65536 + (size_t)(s0 + row) * 64 + c8);
#pragma unroll
        for (int j = 0; j < 8; j++) tile[row * 65 + c8 + j] = val[j];
    }
    __syncthreads();
#pragma unroll
    for (int it = 0; it < 2; it++) {
        const int idx = it * 256 + t;
        const int d = idx >> 3, s8 = (idx & 7) * 8;
        ushort8 o;
#pragma unroll
        for (int j = 0; j < 8; j++) o[j] = (unsigned short)tile[(s8 + j) * 65 + d];
        *(ushort8*)(vt + (size_t)hb * 65536 + (size_t)d * 1024 + s0 + s8) = o;
    }
}

// ---------------- per-hb column mean of vh (for fully-masked rows) ----------------
__global__ void k_vmean(const unsigned short* __restrict__ vh, float* __restrict__ vmean) {
    __shared__ float red[256];
    const int hb = blockIdx.x, t = threadIdx.x;
    const int d = t & 63, part = t >> 6;
    float sum = 0.f;
    const unsigned short* p = vh + (size_t)hb * 65536 + (size_t)part * 256 * 64 + d;
    for (int s = 0; s < 256; s++) sum += bf2f(p[s * 64]);
    red[t] = sum;
    __syncthreads();
    if (part == 0)
        vmean[hb * 64 + d] = (red[d] + red[64 + d] + red[128 + d] + red[192 + d]) * (1.0f / 1024.0f);
}

// ---------------- flash attention, causal + padding mask ----------------
// grid (qt=16, hb=64), 256 threads = 4 waves, wave w owns 16 q-rows.
__global__ __launch_bounds__(256) void k_attn(
    const unsigned short* __restrict__ qh, const unsigned short* __restrict__ kh,
    const unsigned short* __restrict__ vt, const int* __restrict__ mask,
    const float* __restrict__ vmean, float* __restrict__ out) {
    __shared__ unsigned short sK[64 * 64];
    __shared__ unsigned short sV[64 * 64];   // V^T tile: [d][kv]
    __shared__ unsigned short sP[4 * 16 * 64];

    const int qt = blockIdx.x, hb = blockIdx.y;
    const int tid = threadIdx.x;
    const int w = tid >> 6, lane = tid & 63;
    const int c = lane & 15, g = lane >> 4;
    const int q0 = qt * 64 + w * 16;
    const int bidx = hb & 3, head = hb >> 2;

    bf16x8 aq[2];
#pragma unroll
    for (int kk = 0; kk < 2; kk++)
        aq[kk] = *(const bf16x8*)(qh + (size_t)hb * 65536 + (size_t)(q0 + c) * 64 + kk * 32 + g * 8);

    f32x4 oacc[4] = {};
    float lsum[4] = {0.f, 0.f, 0.f, 0.f};
    float mrow[4] = {-1e30f, -1e30f, -1e30f, -1e30f};
    const int* mp = mask + hb * 1024;
    unsigned short* pw = sP + w * 1024;

    for (int t = 0; t <= qt; t++) {
        const int kv0 = t * 64;
        __syncthreads();
        if (w < 2) {                           // waves 0-1 stage K
            const int tl = w * 64 + lane;
#pragma unroll
            for (int i = 0; i < 4; i++) {
                const int idx = i * 128 + tl;
                const int row = idx >> 3, c8 = (idx & 7) * 8;
                bf16x8 val = *(const bf16x8*)(kh + (size_t)hb * 65536 +
                                              (size_t)(kv0 + row) * 64 + c8);
                *(bf16x8*)((char*)sK + swz(row * 128 + c8 * 2)) = val;
            }
        } else {                               // waves 2-3 stage V^T
            const int tl = (w - 2) * 64 + lane;
#pragma unroll
            for (int i = 0; i < 4; i++) {
                const int idx = i * 128 + tl;
                const int d = idx >> 3, s8 = (idx & 7) * 8;
                bf16x8 val = *(const bf16x8*)(vt + (size_t)hb * 65536 +
                                              (size_t)d * 1024 + kv0 + s8);
                *(bf16x8*)((char*)sV + swz(d * 128 + s8 * 2)) = val;
            }
        }
        __syncthreads();

        // S = Q K^T  (S: col=kv=lane&15, row=q=g*4+reg)
        f32x4 sacc[4] = {};
#pragma unroll
        for (int ns = 0; ns < 4; ns++) {
            const int kvl = ns * 16 + c;
#pragma unroll
            for (int kk = 0; kk < 2; kk++) {
                bf16x8 bk = *(const bf16x8*)((char*)sK + swz(kvl * 128 + kk * 64 + g * 16));
                sacc[ns] = __builtin_amdgcn_mfma_f32_16x16x32_bf16(aq[kk], bk, sacc[ns], 0, 0, 0);
            }
        }

        // mask + online softmax
        float sv[4][4];
#pragma unroll
        for (int ns = 0; ns < 4; ns++) {
            const int kvg = kv0 + ns * 16 + c;
            const int mv = mp[kvg];
#pragma unroll
            for (int r = 0; r < 4; r++) {
                const int qg = q0 + g * 4 + r;
                sv[ns][r] = (mv != 0 && kvg <= qg) ? sacc[ns][r] : -1e30f;
            }
        }
#pragma unroll
        for (int r = 0; r < 4; r++) {
            float vmax = fmaxf(fmaxf(sv[0][r], sv[1][r]), fmaxf(sv[2][r], sv[3][r]));
            vmax = fmaxf(vmax, __shfl_xor(vmax, 1, 64));
            vmax = fmaxf(vmax, __shfl_xor(vmax, 2, 64));
            vmax = fmaxf(vmax, __shfl_xor(vmax, 4, 64));
            vmax = fmaxf(vmax, __shfl_xor(vmax, 8, 64));
            const float mnew = fmaxf(mrow[r], vmax);
            const float alpha = __expf(mrow[r] - mnew);
            mrow[r] = mnew;
            float rs = 0.f;
            const int ql = g * 4 + r;
#pragma unroll
            for (int ns = 0; ns < 4; ns++) {
                const float pv = __expf(sv[ns][r] - mnew);
                rs += pv;
                *(unsigned short*)((char*)pw + swz(ql * 128 + (ns * 16 + c) * 2)) = f2bf(pv);
            }
            rs += __shfl_xor(rs, 1, 64);
            rs += __shfl_xor(rs, 2, 64);
            rs += __shfl_xor(rs, 4, 64);
            rs += __shfl_xor(rs, 8, 64);
            lsum[r] = lsum[r] * alpha + rs;
#pragma unroll
            for (int nd = 0; nd < 4; nd++) oacc[nd][r] *= alpha;
        }

        asm volatile("s_waitcnt lgkmcnt(0)" ::: "memory");
        // O += P V   (A=P rows=q, B=V cols=d from V^T tile)
#pragma unroll
        for (int ks = 0; ks < 2; ks++) {
            const bf16x8 ap = *(const bf16x8*)((char*)pw + swz(c * 128 + ks * 64 + g * 16));
#pragma unroll
            for (int nd = 0; nd < 4; nd++) {
                const int d = nd * 16 + c;
                const bf16x8 bv = *(const bf16x8*)((char*)sV + swz(d * 128 + ks * 64 + g * 16));
                oacc[nd] = __builtin_amdgcn_mfma_f32_16x16x32_bf16(ap, bv, oacc[nd], 0, 0, 0);
            }
        }
    }

#pragma unroll
    for (int nd = 0; nd < 4; nd++)
#pragma unroll
        for (int r = 0; r < 4; r++) {
            const int s = q0 + g * 4 + r;
            const int dcol = nd * 16 + c;
            // fully-masked row: reference softmax is uniform over ALL 1024 keys
            const float val = (mrow[r] < -5e29f) ? vmean[hb * 64 + dcol]
                                                 : oacc[nd][r] / lsum[r];
            out[(size_t)bidx * 1048576 + (size_t)s * 1024 + head * 64 + dcol] = val;
        }
}

extern "C" void kernel_launch(void* const* d_in, const int* in_sizes, int n_in,
                              void* d_out, int out_size, void* d_ws, size_t ws_size,
                              hipStream_t stream) {
    const float* q  = (const float*)d_in[0];
    const float* k  = (const float*)d_in[1];
    const float* v  = (const float*)d_in[2];
    const int* mask = (const int*)d_in[3];
    const float* Wq = (const float*)d_in[4];
    const float* bq = (const float*)d_in[5];
    const float* Wk = (const float*)d_in[6];
    const float* bk = (const float*)d_in[7];
    const float* Wv = (const float*)d_in[8];
    const float* bv = (const float*)d_in[9];
    float* out = (float*)d_out;

    unsigned short* qb = (unsigned short*)d_ws;
    unsigned short* kb = qb + 4194304;
    unsigned short* vb = kb + 4194304;
    unsigned short* wt = vb + 4194304;     // 3 * 1048576
    unsigned short* qh = wt + 3 * 1048576;
    unsigned short* kh = qh + 4194304;
    unsigned short* vh = kh + 4194304;
    unsigned short* vt = vh + 4194304;
    float* vmean = (float*)(vt + 4194304); // 64*64 floats

    k_convert<<<dim3(2048, 1, 3), 256, 0, stream>>>(q, k, v, qb, kb, vb);
    k_convw<<<dim3(16, 16, 3), 256, 0, stream>>>(Wq, Wk, Wv, wt);
    k_proj<<<dim3(8, 32, 3), 256, 0, stream>>>(qb, kb, vb, wt, bq, bk, bv, qh, kh, vh);
    k_trv<<<dim3(16, 64), 256, 0, stream>>>(vh, vt);
    k_vmean<<<64, 256, 0, stream>>>(vh, vmean);
    k_attn<<<dim3(16, 64), 256, 0, stream>>>(qh, kh, vt, mask, vmean, out);
}

// Round 2
// 220.892 us; speedup vs baseline: 1.1032x; 1.1032x over previous
//
#include <hip/hip_runtime.h>
#include <stdint.h>

#define DEV __device__ __forceinline__

typedef __attribute__((ext_vector_type(4))) float f32x4;
typedef __attribute__((ext_vector_type(8))) __bf16 bf16x8;
typedef __attribute__((ext_vector_type(8))) unsigned short ushort8;

DEV unsigned short f2bf(float f) {
    union { float f; unsigned int u; } v; v.f = f;
    unsigned int r = v.u + 0x7FFFu + ((v.u >> 16) & 1u);
    return (unsigned short)(r >> 16);
}
DEV float bf2f(unsigned short u) {
    union { unsigned int u; float f; } v; v.u = ((unsigned int)u) << 16;
    return v.f;
}
// XOR-swizzle a linear LDS byte offset (128B rows): byte ^= ((row&7)<<4)
DEV int swz(int o) { return o ^ ((o >> 3) & 0x70); }

DEV void gload_lds16(const void* gptr, void* lptr) {
    __builtin_amdgcn_global_load_lds(
        (const __attribute__((address_space(1))) unsigned int*)gptr,
        (__attribute__((address_space(3))) unsigned int*)lptr, 16, 0, 0);
}

// ---------------- fp32 -> bf16 convert of q,k,v ----------------
__global__ void k_convert(const float* __restrict__ q, const float* __restrict__ k,
                          const float* __restrict__ v, unsigned short* __restrict__ qb,
                          unsigned short* __restrict__ kb, unsigned short* __restrict__ vb) {
    const int z = blockIdx.z;
    const float* src = z == 0 ? q : (z == 1 ? k : v);
    unsigned short* dst = z == 0 ? qb : (z == 1 ? kb : vb);
    const size_t idx = ((size_t)blockIdx.x * 256 + threadIdx.x) * 8;
    f32x4 a = *(const f32x4*)(src + idx);
    f32x4 b = *(const f32x4*)(src + idx + 4);
    ushort8 o;
    o[0] = f2bf(a[0]); o[1] = f2bf(a[1]); o[2] = f2bf(a[2]); o[3] = f2bf(a[3]);
    o[4] = f2bf(b[0]); o[5] = f2bf(b[1]); o[6] = f2bf(b[2]); o[7] = f2bf(b[3]);
    *(ushort8*)(dst + idx) = o;
}

// ---------------- W (fp32 [k][n]) -> Wt (bf16 [n][k]) ----------------
__global__ void k_convw(const float* __restrict__ Wq, const float* __restrict__ Wk,
                        const float* __restrict__ Wv, unsigned short* __restrict__ wt) {
    __shared__ float tile[64 * 65];
    const int z = blockIdx.z;
    const float* W = z == 0 ? Wq : (z == 1 ? Wk : Wv);
    unsigned short* dst = wt + (size_t)z * 1048576;
    const int k0 = blockIdx.x * 64, n0 = blockIdx.y * 64;
    const int t = threadIdx.x;
#pragma unroll
    for (int i = 0; i < 4; i++) {
        const int idx = i * 256 + t;
        const int row = idx >> 4, c4 = (idx & 15) * 4;
        f32x4 val = *(const f32x4*)(W + (size_t)(k0 + row) * 1024 + n0 + c4);
#pragma unroll
        for (int j = 0; j < 4; j++) tile[row * 65 + c4 + j] = val[j];
    }
    __syncthreads();
#pragma unroll
    for (int i = 0; i < 2; i++) {
        const int idx = i * 256 + t;
        const int nrow = idx >> 3, c8 = (idx & 7) * 8;
        ushort8 o;
#pragma unroll
        for (int j = 0; j < 8; j++) o[j] = f2bf(tile[(c8 + j) * 65 + nrow]);
        *(ushort8*)(dst + (size_t)(n0 + nrow) * 1024 + k0 + c8) = o;
    }
}

// ---------------- projection GEMM: C = A(4096x1024) * Wt^T + bias ----------------
__global__ __launch_bounds__(256) void k_proj(
    const unsigned short* __restrict__ qb, const unsigned short* __restrict__ kb,
    const unsigned short* __restrict__ vb, const unsigned short* __restrict__ wt,
    const float* __restrict__ bq, const float* __restrict__ bk, const float* __restrict__ bv,
    unsigned short* __restrict__ qh, unsigned short* __restrict__ kh,
    unsigned short* __restrict__ vh) {
    const int z = blockIdx.z;
    const unsigned short* A  = z == 0 ? qb : (z == 1 ? kb : vb);
    const unsigned short* Bt = wt + (size_t)z * 1048576;
    const float* bias = z == 0 ? bq : (z == 1 ? bk : bv);
    unsigned short* outp = z == 0 ? qh : (z == 1 ? kh : vh);
    const float scale = z == 0 ? 0.125f : 1.0f;   // fold 1/sqrt(dh) into q

    __shared__ unsigned short sA[128 * 64];
    __shared__ unsigned short sB[128 * 64];

    const int tid = threadIdx.x;
    const int w = tid >> 6, lane = tid & 63;
    const int c = lane & 15, gq = lane >> 4;
    const int wrow = w >> 1, wcol = w & 1;
    const int m0 = blockIdx.y * 128, n0 = blockIdx.x * 128;
    const int lr = lane >> 3;
    const int lcs = ((lane & 7) ^ (lane >> 3)) * 8;

    f32x4 acc[4][4] = {};

    for (int kt = 0; kt < 16; kt++) {
        __syncthreads();
        const int kb0 = kt * 64;
#pragma unroll
        for (int i = 0; i < 4; i++) {
            const int rbase = w * 32 + i * 8;
            gload_lds16(A  + (size_t)(m0 + rbase + lr) * 1024 + kb0 + lcs,
                        (char*)sA + rbase * 128);
            gload_lds16(Bt + (size_t)(n0 + rbase + lr) * 1024 + kb0 + lcs,
                        (char*)sB + rbase * 128);
        }
        __syncthreads();
#pragma unroll
        for (int kk = 0; kk < 2; kk++) {
            bf16x8 af[4], bfr[4];
#pragma unroll
            for (int i = 0; i < 4; i++) {
                af[i]  = *(const bf16x8*)((char*)sA +
                          swz((wrow * 64 + i * 16 + c) * 128 + kk * 64 + gq * 16));
                bfr[i] = *(const bf16x8*)((char*)sB +
                          swz((wcol * 64 + i * 16 + c) * 128 + kk * 64 + gq * 16));
            }
#pragma unroll
            for (int mi = 0; mi < 4; mi++)
#pragma unroll
                for (int ni = 0; ni < 4; ni++)
                    acc[mi][ni] = __builtin_amdgcn_mfma_f32_16x16x32_bf16(
                        af[mi], bfr[ni], acc[mi][ni], 0, 0, 0);
        }
    }

    float bvals[4];
#pragma unroll
    for (int ni = 0; ni < 4; ni++) bvals[ni] = bias[n0 + wcol * 64 + ni * 16 + c];

#pragma unroll
    for (int mi = 0; mi < 4; mi++)
#pragma unroll
        for (int ni = 0; ni < 4; ni++) {
            const int n = n0 + wcol * 64 + ni * 16 + c;
            const int head = n >> 6, d = n & 63;
#pragma unroll
            for (int r = 0; r < 4; r++) {
                const int m = m0 + wrow * 64 + mi * 16 + gq * 4 + r;
                const int bb = m >> 10, s = m & 1023;
                const float val = (acc[mi][ni][r] + bvals[ni]) * scale;
                outp[(size_t)((head << 2) + bb) * 65536 + (size_t)s * 64 + d] = f2bf(val);
            }
        }
}

// ---------------- vh [hb][s][d] -> vt [hb][d][s] ----------------
__global__ void k_trv(const unsigned short* __restrict__ vh, unsigned short* __restrict__ vt) {
    __shared__ unsigned int tile[64 * 65];
    const int hb = blockIdx.y, s0 = blockIdx.x * 64;
    const int t = threadIdx.x;
#pragma unroll
    for (int it = 0; it < 2; it++) {
        const int idx = it * 256 + t;
        const int row = idx >> 3, c8 = (idx & 7) * 8;
        ushort8 val = *(const ushort8*)(vh + (size_t)hb * 65536 + (size_t)(s0 + row) * 64 + c8);
#pragma unroll
        for (int j = 0; j < 8; j++) tile[row * 65 + c8 + j] = val[j];
    }
    __syncthreads();
#pragma unroll
    for (int it = 0; it < 2; it++) {
        const int idx = it * 256 + t;
        const int d = idx >> 3, s8 = (idx & 7) * 8;
        ushort8 o;
#pragma unroll
        for (int j = 0; j < 8; j++) o[j] = (unsigned short)tile[(s8 + j) * 65 + d];
        *(ushort8*)(vt + (size_t)hb * 65536 + (size_t)d * 1024 + s0 + s8) = o;
    }
}

// ---------------- per-hb column mean of v (reads vt rows, coalesced) ----------------
__global__ void k_vmean(const unsigned short* __restrict__ vt, float* __restrict__ vmean) {
    __shared__ float red[256];
    const int hb = blockIdx.x, t = threadIdx.x;
    const int d = t >> 2, part = t & 3;
    const unsigned short* p = vt + (size_t)hb * 65536 + (size_t)d * 1024 + part * 256;
    float sum = 0.f;
#pragma unroll 4
    for (int i = 0; i < 32; i++) {
        ushort8 v8 = *(const ushort8*)(p + i * 8);
#pragma unroll
        for (int j = 0; j < 8; j++) sum += bf2f(v8[j]);
    }
    red[t] = sum;
    __syncthreads();
    if (part == 0)
        vmean[hb * 64 + d] = (red[t] + red[t + 1] + red[t + 2] + red[t + 3]) * (1.0f / 1024.0f);
}

// ---------------- flash attention, causal + padding mask ----------------
// grid (8, 64): block b owns q-tiles {b, 15-b} (uniform 17 tile-computes).
// 256 threads = 4 waves, wave w owns rows [w*16, w*16+16) of each q-tile.
// K/V double-buffered via global_load_lds (pre-swizzled source), counted vmcnt.
__global__ __launch_bounds__(256) void k_attn(
    const unsigned short* __restrict__ qh, const unsigned short* __restrict__ kh,
    const unsigned short* __restrict__ vt, const int* __restrict__ mask,
    const float* __restrict__ vmean, float* __restrict__ out) {
    __shared__ unsigned short sK[2][64 * 64];
    __shared__ unsigned short sV[2][64 * 64];   // V^T tiles: [d][kv]
    __shared__ unsigned short sP[2][4 * 16 * 64];

    const int b = blockIdx.x, hb = blockIdx.y;
    const int tid = threadIdx.x;
    const int w = tid >> 6, lane = tid & 63;
    const int c = lane & 15, g = lane >> 4;
    const int qtA = b, qtB = 15 - b;
    const int tmax = qtB;
    const int q0A = qtA * 64 + w * 16, q0B = qtB * 64 + w * 16;
    const int bidx = hb & 3, head = hb >> 2;
    const size_t hboff = (size_t)hb * 65536;
    const int* mp = mask + hb * 1024;

    bf16x8 aqA[2], aqB[2];
#pragma unroll
    for (int kk = 0; kk < 2; kk++) {
        aqA[kk] = *(const bf16x8*)(qh + hboff + (size_t)(q0A + c) * 64 + kk * 32 + g * 8);
        aqB[kk] = *(const bf16x8*)(qh + hboff + (size_t)(q0B + c) * 64 + kk * 32 + g * 8);
    }

    f32x4 oaccA[4] = {}, oaccB[4] = {};
    float lsumA[4] = {0.f, 0.f, 0.f, 0.f}, lsumB[4] = {0.f, 0.f, 0.f, 0.f};
    float mrowA[4] = {-1e30f, -1e30f, -1e30f, -1e30f};
    float mrowB[4] = {-1e30f, -1e30f, -1e30f, -1e30f};

    const int srow = tid >> 3, sch = tid & 7;                // 32 rows x 8 chunks / pass
    const int ssc = (sch ^ (srow & 7)) * 8;                  // pre-swizzled source col

    auto stage = [&](int t, int buf) {
        const int kv0 = t * 64;
#pragma unroll
        for (int i = 0; i < 2; i++) {
            const int row = i * 32 + srow;
            gload_lds16(kh + hboff + (size_t)(kv0 + row) * 64 + ssc,
                        (char*)sK[buf] + row * 128 + sch * 16);
        }
#pragma unroll
        for (int i = 0; i < 2; i++) {
            const int row = i * 32 + srow;                   // row = d here
            gload_lds16(vt + hboff + (size_t)row * 1024 + kv0 + ssc,
                        (char*)sV[buf] + row * 128 + sch * 16);
        }
    };

    auto compute_tile = [&](int kv0, int q0, const bf16x8* aq, f32x4* oacc,
                            float* lsum, float* mrow, unsigned short* pw,
                            const unsigned short* sKc, const unsigned short* sVc) {
        // S = Q K^T
        f32x4 sacc[4] = {};
#pragma unroll
        for (int ns = 0; ns < 4; ns++) {
            const int kvl = ns * 16 + c;
#pragma unroll
            for (int kk = 0; kk < 2; kk++) {
                bf16x8 bk = *(const bf16x8*)((char*)sKc + swz(kvl * 128 + kk * 64 + g * 16));
                sacc[ns] = __builtin_amdgcn_mfma_f32_16x16x32_bf16(aq[kk], bk, sacc[ns], 0, 0, 0);
            }
        }
        // mask + online softmax
        float sv[4][4];
#pragma unroll
        for (int ns = 0; ns < 4; ns++) {
            const int kvg = kv0 + ns * 16 + c;
            const int mv = mp[kvg];
#pragma unroll
            for (int r = 0; r < 4; r++) {
                const int qg = q0 + g * 4 + r;
                sv[ns][r] = (mv != 0 && kvg <= qg) ? sacc[ns][r] : -1e30f;
            }
        }
#pragma unroll
        for (int r = 0; r < 4; r++) {
            float vmax = fmaxf(fmaxf(sv[0][r], sv[1][r]), fmaxf(sv[2][r], sv[3][r]));
            vmax = fmaxf(vmax, __shfl_xor(vmax, 1, 64));
            vmax = fmaxf(vmax, __shfl_xor(vmax, 2, 64));
            vmax = fmaxf(vmax, __shfl_xor(vmax, 4, 64));
            vmax = fmaxf(vmax, __shfl_xor(vmax, 8, 64));
            const float mnew = fmaxf(mrow[r], vmax);
            const float alpha = __expf(mrow[r] - mnew);
            mrow[r] = mnew;
            float rs = 0.f;
            const int ql = g * 4 + r;
#pragma unroll
            for (int ns = 0; ns < 4; ns++) {
                const float pv = __expf(sv[ns][r] - mnew);
                rs += pv;
                *(unsigned short*)((char*)pw + swz(ql * 128 + (ns * 16 + c) * 2)) = f2bf(pv);
            }
            rs += __shfl_xor(rs, 1, 64);
            rs += __shfl_xor(rs, 2, 64);
            rs += __shfl_xor(rs, 4, 64);
            rs += __shfl_xor(rs, 8, 64);
            lsum[r] = lsum[r] * alpha + rs;
#pragma unroll
            for (int nd = 0; nd < 4; nd++) oacc[nd][r] *= alpha;
        }
        asm volatile("s_waitcnt lgkmcnt(0)" ::: "memory");
        // O += P V
#pragma unroll
        for (int ks = 0; ks < 2; ks++) {
            const bf16x8 ap = *(const bf16x8*)((char*)pw + swz(c * 128 + ks * 64 + g * 16));
#pragma unroll
            for (int nd = 0; nd < 4; nd++) {
                const int d = nd * 16 + c;
                const bf16x8 bv = *(const bf16x8*)((char*)sVc + swz(d * 128 + ks * 64 + g * 16));
                oacc[nd] = __builtin_amdgcn_mfma_f32_16x16x32_bf16(ap, bv, oacc[nd], 0, 0, 0);
            }
        }
    };

    stage(0, 0);
    for (int t = 0; t <= tmax; t++) {
        const int cur = t & 1;
        if (t < tmax) {
            stage(t + 1, cur ^ 1);
            asm volatile("s_waitcnt vmcnt(4)" ::: "memory");   // tile t's 4 loads done
        } else {
            asm volatile("s_waitcnt vmcnt(0)" ::: "memory");
        }
        __builtin_amdgcn_s_barrier();
        __builtin_amdgcn_sched_barrier(0);
        const int kv0 = t * 64;
        if (t <= qtA)
            compute_tile(kv0, q0A, aqA, oaccA, lsumA, mrowA,
                         sP[0] + w * 1024, sK[cur], sV[cur]);
        compute_tile(kv0, q0B, aqB, oaccB, lsumB, mrowB,
                     sP[1] + w * 1024, sK[cur], sV[cur]);
        __builtin_amdgcn_sched_barrier(0);
        __builtin_amdgcn_s_barrier();                          // reads done before next stage
        __builtin_amdgcn_sched_barrier(0);
    }

    auto write_out = [&](int q0, f32x4* oacc, float* lsum, float* mrow) {
#pragma unroll
        for (int nd = 0; nd < 4; nd++)
#pragma unroll
            for (int r = 0; r < 4; r++) {
                const int s = q0 + g * 4 + r;
                const int dcol = nd * 16 + c;
                const float val = (mrow[r] < -5e29f) ? vmean[hb * 64 + dcol]
                                                     : oacc[nd][r] / lsum[r];
                out[(size_t)bidx * 1048576 + (size_t)s * 1024 + head * 64 + dcol] = val;
            }
    };
    write_out(q0A, oaccA, lsumA, mrowA);
    write_out(q0B, oaccB, lsumB, mrowB);
}

extern "C" void kernel_launch(void* const* d_in, const int* in_sizes, int n_in,
                              void* d_out, int out_size, void* d_ws, size_t ws_size,
                              hipStream_t stream) {
    const float* q  = (const float*)d_in[0];
    const float* k  = (const float*)d_in[1];
    const float* v  = (const float*)d_in[2];
    const int* mask = (const int*)d_in[3];
    const float* Wq = (const float*)d_in[4];
    const float* bq = (const float*)d_in[5];
    const float* Wk = (const float*)d_in[6];
    const float* bk = (const float*)d_in[7];
    const float* Wv = (const float*)d_in[8];
    const float* bv = (const float*)d_in[9];
    float* out = (float*)d_out;

    unsigned short* qb = (unsigned short*)d_ws;
    unsigned short* kb = qb + 4194304;
    unsigned short* vb = kb + 4194304;
    unsigned short* wt = vb + 4194304;     // 3 * 1048576
    unsigned short* qh = wt + 3 * 1048576;
    unsigned short* kh = qh + 4194304;
    unsigned short* vh = kh + 4194304;
    unsigned short* vt = vh + 4194304;
    float* vmean = (float*)(vt + 4194304); // 64*64 floats

    k_convert<<<dim3(2048, 1, 3), 256, 0, stream>>>(q, k, v, qb, kb, vb);
    k_convw<<<dim3(16, 16, 3), 256, 0, stream>>>(Wq, Wk, Wv, wt);
    k_proj<<<dim3(8, 32, 3), 256, 0, stream>>>(qb, kb, vb, wt, bq, bk, bv, qh, kh, vh);
    k_trv<<<dim3(16, 64), 256, 0, stream>>>(vh, vt);
    k_vmean<<<64, 256, 0, stream>>>(vt, vmean);
    k_attn<<<dim3(8, 64), 256, 0, stream>>>(qh, kh, vt, mask, vmean, out);
}